// Round 11
// baseline (768.819 us; speedup 1.0000x reference)
//
#include <hip/hip_runtime.h>
#include <stdint.h>

// GATConv fused v11: 2 blocks/CU. CCH=8 (512 blocks), BR=128, single-buffered
// K/V (co-resident block hides staging/softmax stalls), per-wave P stride-64
// XOR-swizzled -> LDS exactly 80KB/block. pO partials f16 (fits ws, halves
// WRITE). Deferred l-sum kept (R10 win). launch_bounds(512,4) caps VGPR 128.

typedef _Float16 f16;
typedef unsigned short u16;
typedef __attribute__((ext_vector_type(8))) _Float16 f16x8;
typedef __attribute__((ext_vector_type(4))) _Float16 f16x4;
typedef __attribute__((ext_vector_type(4))) float f32x4;

#define NN 8192
#define DD 256
#define BR 128
#define BC 64
#define CCH 8
#define COLS (NN / CCH)  // 1024
#define NIT (COLS / BC)  // 16

#define MFMA(a, b, c) __builtin_amdgcn_mfma_f32_16x16x32_f16((a), (b), (c), 0, 0, 0)

__device__ __forceinline__ void gl2lds16(const void* g, void* l) {
    __builtin_amdgcn_global_load_lds(
        (const __attribute__((address_space(1))) unsigned int*)g,
        (__attribute__((address_space(3))) unsigned int*)l, 16, 0, 0);
}

__device__ __forceinline__ u16 f16bits(f16 h) {
    union { f16 h; u16 u; } c;
    c.h = h;
    return c.u;
}

// P row swizzle: distinct 16B-block offsets across quads (verified bank-clean
// for both the 4x b16 write groups and the b128 A-frag reads)
__device__ __forceinline__ int pswz(int row) { return (row ^ (row >> 2)) & 7; }

// ---------------- split X to fp16 hi/lo (4 elems/thread) ----------------
__global__ void splitX_kernel(const float4* __restrict__ X, f16x4* __restrict__ Xh,
                              f16x4* __restrict__ Xl) {
    const int i = blockIdx.x * blockDim.x + threadIdx.x;  // 524288
    const float4 v = X[i];
    const f16 h0 = (f16)v.x, h1 = (f16)v.y, h2 = (f16)v.z, h3 = (f16)v.w;
    f16x4 H = {h0, h1, h2, h3};
    f16x4 L = {(f16)(v.x - (float)h0), (f16)(v.y - (float)h1), (f16)(v.z - (float)h2),
               (f16)(v.w - (float)h3)};
    Xh[i] = H;
    Xl[i] = L;
}

// W[k][n] (3 mats 256x256) -> Wt[(mat*256+n)][k] fp16 hi/lo (transposed)
__global__ void splitW_kernel(const float* __restrict__ Wq, const float* __restrict__ Wk,
                              const float* __restrict__ Wv, f16* __restrict__ WtH,
                              f16* __restrict__ WtL) {
    const int i = blockIdx.x * blockDim.x + threadIdx.x;  // 3*65536
    const int mat = i >> 16;
    const int k = (i >> 8) & 255;
    const int n = i & 255;
    const float* W = (mat == 0) ? Wq : ((mat == 1) ? Wk : Wv);
    const float v = W[k * 256 + n];
    const f16 h = (f16)v;
    const size_t o = (size_t)(mat * 256 + n) * 256 + k;
    WtH[o] = h;
    WtL[o] = (f16)(v - (float)h);
}

// ---------------- QKV GEMM: LDS-staged W chunks, X frags in registers ----------------
__global__ __launch_bounds__(256, 2) void qkv_kernel(
    const f16* __restrict__ Xh, const f16* __restrict__ Xl,
    const f16* __restrict__ WtH, const f16* __restrict__ WtL,
    f16* __restrict__ Qh, f16* __restrict__ Ql,
    f16* __restrict__ Kh, f16* __restrict__ Vt) {
    __shared__ f16 Wh[64 * 256];
    __shared__ f16 Wl[64 * 256];
    const int lane = threadIdx.x & 63;
    const int w = threadIdx.x >> 6;
    const int l15 = lane & 15;
    const int quad = lane >> 4;
    const int r0 = blockIdx.x * 64;
    const int mat = blockIdx.y;

    f16x8 xh[8], xl[8];
    const size_t xb = (size_t)(r0 + w * 16 + l15) * DD + quad * 8;
#pragma unroll
    for (int kc = 0; kc < 8; ++kc) {
        xh[kc] = *(const f16x8*)(Xh + xb + kc * 32);
        xl[kc] = *(const f16x8*)(Xl + xb + kc * 32);
    }
    const int orow = r0 + w * 16 + quad * 4;

#pragma unroll 1
    for (int c = 0; c < 4; ++c) {
        const int nb = mat * 256 + c * 64;
#pragma unroll
        for (int i = 0; i < 8; ++i) {
            const int r = w * 16 + i * 2 + (lane >> 5);
            gl2lds16(WtH + (size_t)(nb + r) * DD + (((lane & 31) ^ (r & 7)) * 8),
                     &Wh[(w * 16 + i * 2) * 256]);
        }
#pragma unroll
        for (int i = 0; i < 8; ++i) {
            const int r = w * 16 + i * 2 + (lane >> 5);
            gl2lds16(WtL + (size_t)(nb + r) * DD + (((lane & 31) ^ (r & 7)) * 8),
                     &Wl[(w * 16 + i * 2) * 256]);
        }
        __syncthreads();

        const f32x4 fzero = {0.f, 0.f, 0.f, 0.f};
        f32x4 acc[4];
#pragma unroll
        for (int nt = 0; nt < 4; ++nt) acc[nt] = fzero;
#pragma unroll
        for (int kc = 0; kc < 8; ++kc)
#pragma unroll
            for (int nt = 0; nt < 4; ++nt) {
                const int r = nt * 16 + l15;
                const int blk = (((kc * 4 + quad) ^ (r & 7)) * 8);
                const f16x8 wh = *(const f16x8*)&Wh[r * 256 + blk];
                const f16x8 wl = *(const f16x8*)&Wl[r * 256 + blk];
                acc[nt] = MFMA(xh[kc], wh, acc[nt]);
                acc[nt] = MFMA(xh[kc], wl, acc[nt]);
                acc[nt] = MFMA(xl[kc], wh, acc[nt]);
            }

        if (mat == 0) {
#pragma unroll
            for (int nt = 0; nt < 4; ++nt)
#pragma unroll
                for (int rg = 0; rg < 4; ++rg) {
                    const int col = c * 64 + nt * 16 + l15;
                    const float v = acc[nt][rg];
                    const f16 h = (f16)v;
                    Qh[(size_t)(orow + rg) * DD + col] = h;
                    Ql[(size_t)(orow + rg) * DD + col] = (f16)(v - (float)h);
                }
        } else if (mat == 1) {
#pragma unroll
            for (int nt = 0; nt < 4; ++nt)
#pragma unroll
                for (int rg = 0; rg < 4; ++rg) {
                    const int col = c * 64 + nt * 16 + l15;
                    Kh[(size_t)(orow + rg) * DD + col] = (f16)acc[nt][rg];
                }
        } else {
#pragma unroll
            for (int nt = 0; nt < 4; ++nt) {
                const int n = c * 64 + nt * 16 + l15;
                ushort4 pk;
                pk.x = f16bits((f16)acc[nt][0]);
                pk.y = f16bits((f16)acc[nt][1]);
                pk.z = f16bits((f16)acc[nt][2]);
                pk.w = f16bits((f16)acc[nt][3]);
                *(ushort4*)(Vt + (size_t)n * NN + orow) = pk;
            }
        }
        __syncthreads();
    }
}

// ---------------- flash kernel v11 ----------------
// grid 512 linear: cch = bid&7 (pins chunk to XCD), rowblk = bid>>3, BR=128.
// 8 waves x 16 rows, wave-local softmax, single-buffered K/V, 2 barriers/iter;
// the co-resident second block hides staging/softmax stalls.
__global__ __launch_bounds__(512, 4) void flash_kernel(
    const f16* __restrict__ Qh, const f16* __restrict__ Ql,
    const f16* __restrict__ Kh, const f16* __restrict__ Vt,
    const int* __restrict__ A,
    f16* __restrict__ pO, float* __restrict__ pM, float* __restrict__ pL) {
    __shared__ f16 Klds[64 * 256];    // 32 KB, [j][k] XOR-swizzled by j&7
    __shared__ f16 Vlds[256 * 64];    // 32 KB, [n][j] swizzled by n&7
    __shared__ f16 Plds[8][16 * 64];  // 16 KB, per-wave, pswz 16B-block swizzle
                                      // total: exactly 80 KB -> 2 blocks/CU

    const int lane = threadIdx.x & 63;
    const int w = threadIdx.x >> 6;  // 0..7
    const int l15 = lane & 15;
    const int quad = lane >> 4;
    const int bid = blockIdx.x;
    const int cch = bid & 7;
    const int r0 = (bid >> 3) * BR;
    const int col0 = cch * COLS;

    // Q fragments resident (A-layout m=l15, k=quad*8+i), hi+lo
    f16x8 qh[8], ql[8];
    {
        const size_t qb = (size_t)(r0 + w * 16 + l15) * DD + quad * 8;
#pragma unroll
        for (int kc = 0; kc < 8; ++kc) {
            qh[kc] = *(const f16x8*)(Qh + qb + kc * 32);
            ql[kc] = *(const f16x8*)(Ql + qb + kc * 32);
        }
    }

    const f32x4 fzero = {0.f, 0.f, 0.f, 0.f};
    f32x4 accO[16];
#pragma unroll
    for (int i = 0; i < 16; ++i) accO[i] = fzero;
    float mrow[4], lpart[4];  // per-lane l partials, reduced in epilogue
#pragma unroll
    for (int r = 0; r < 4; ++r) {
        mrow[r] = -1e30f;
        lpart[r] = 0.f;
    }
    const int growb = r0 + w * 16 + quad * 4;
    f16* Pw = &Plds[w][0];

#pragma unroll 1
    for (int it = 0; it < NIT; ++it) {
        const int j0 = col0 + it * BC;

        // stage K rows w*8..+8 and V n-rows w*32..+32 (single buffer)
#pragma unroll
        for (int i = 0; i < 4; ++i) {
            const int r = w * 8 + i * 2 + (lane >> 5);
            gl2lds16(Kh + (size_t)(j0 + r) * DD + (((lane & 31) ^ (r & 7)) * 8),
                     &Klds[(w * 8 + i * 2) * 256]);
        }
#pragma unroll
        for (int i = 0; i < 4; ++i) {
            const int n = w * 32 + i * 8 + (lane >> 3);
            gl2lds16(Vt + (size_t)n * NN + j0 + (((lane & 7) ^ (n & 7)) * 8),
                     &Vlds[(w * 32 + i * 8) * 64]);
        }

        // adjacency (issued pre-barrier; latency overlaps the staging drain)
        int av[4][4];
#pragma unroll
        for (int rgi = 0; rgi < 4; ++rgi)
#pragma unroll
            for (int jt = 0; jt < 4; ++jt)
                av[rgi][jt] = __builtin_nontemporal_load(
                    A + (size_t)(growb + rgi) * NN + j0 + jt * 16 + l15);

        __syncthreads();  // B1: staging visible (co-resident block computes now)

        // S = (Qh+Ql)·Kh^T : 16 rows x 64 cols per wave
        f32x4 accS[4];
#pragma unroll
        for (int jt = 0; jt < 4; ++jt) accS[jt] = fzero;
#pragma unroll
        for (int kc = 0; kc < 8; ++kc)
#pragma unroll
            for (int jt = 0; jt < 4; ++jt) {
                const int r = jt * 16 + l15;
                const f16x8 kf =
                    *(const f16x8*)&Klds[r * 256 + (((kc * 4 + quad) ^ (r & 7)) * 8)];
                accS[jt] = MFMA(qh[kc], kf, accS[jt]);
                accS[jt] = MFMA(ql[kc], kf, accS[jt]);
            }

        // wave-local online softmax (f32 shfl max; l-sum deferred)
        float alpha[4];
#pragma unroll
        for (int rgi = 0; rgi < 4; ++rgi) {
            const int gr = growb + rgi;
            float mx = -3.0e38f;
#pragma unroll
            for (int jt = 0; jt < 4; ++jt) {
                const int gc = j0 + jt * 16 + l15;
                const float s = (av[rgi][jt] != 0 || gr == gc) ? accS[jt][rgi] : -3.0e38f;
                accS[jt][rgi] = s;
                mx = fmaxf(mx, s);
            }
#pragma unroll
            for (int off = 1; off < 16; off <<= 1) mx = fmaxf(mx, __shfl_xor(mx, off, 64));
            const float mnew = fmaxf(mrow[rgi], mx);
            alpha[rgi] = __expf(mrow[rgi] - mnew);
            mrow[rgi] = mnew;
            float rs = 0.f;
            const int lrow = quad * 4 + rgi;
#pragma unroll
            for (int jt = 0; jt < 4; ++jt) {
                const float s = accS[jt][rgi];
                const float e = (s > -1.0e37f) ? __expf(s - mnew) : 0.f;
                rs += e;
                const int col = jt * 16 + l15;
                Pw[lrow * 64 + (((col >> 3) ^ pswz(lrow)) * 8) + (col & 7)] = (f16)e;
            }
            lpart[rgi] = lpart[rgi] * alpha[rgi] + rs;
        }
#pragma unroll
        for (int nt = 0; nt < 16; ++nt)
#pragma unroll
            for (int rgi = 0; rgi < 4; ++rgi) accO[nt][rgi] *= alpha[rgi];

        // P A-frags (per-wave LDS round trip; in-order, no barrier)
        f16x8 pf[2];
        pf[0] = *(const f16x8*)&Pw[l15 * 64 + (((0 * 4 + quad) ^ pswz(l15)) * 8)];
        pf[1] = *(const f16x8*)&Pw[l15 * 64 + (((1 * 4 + quad) ^ pswz(l15)) * 8)];

        // PV: 16 rows x 256 n per wave
#pragma unroll
        for (int nt = 0; nt < 16; ++nt)
#pragma unroll
            for (int kc2 = 0; kc2 < 2; ++kc2) {
                const int n = nt * 16 + l15;
                const f16x8 vf =
                    *(const f16x8*)&Vlds[n * 64 + (((kc2 * 4 + quad) ^ (n & 7)) * 8)];
                accO[nt] = MFMA(pf[kc2], vf, accO[nt]);
            }

        __syncthreads();  // B2: compute done; LDS reusable next iter
    }

    // epilogue: reduce per-lane l partials across 16 lanes (once)
#pragma unroll
    for (int rgi = 0; rgi < 4; ++rgi)
#pragma unroll
        for (int off = 1; off < 16; off <<= 1)
            lpart[rgi] += __shfl_xor(lpart[rgi], off, 64);

    // write partials (f16 unnormalized O: |O| <= l*maxV < 1e4 << f16 max)
#pragma unroll
    for (int nt = 0; nt < 16; ++nt)
#pragma unroll
        for (int rgi = 0; rgi < 4; ++rgi)
            pO[((size_t)cch * NN + growb + rgi) * DD + nt * 16 + l15] =
                (f16)accO[nt][rgi];
    if (l15 == 0) {
#pragma unroll
        for (int rgi = 0; rgi < 4; ++rgi) {
            pM[(size_t)cch * NN + growb + rgi] = mrow[rgi];
            pL[(size_t)cch * NN + growb + rgi] = lpart[rgi];
        }
    }
}

// ---------------- merge partials (8 rows/block) ----------------
__global__ __launch_bounds__(256) void merge_kernel(const f16* __restrict__ pO,
                                                    const float* __restrict__ pM,
                                                    const float* __restrict__ pL,
                                                    float* __restrict__ out) {
    const int n = threadIdx.x;
#pragma unroll 1
    for (int rr = 0; rr < 8; ++rr) {
        const int row = blockIdx.x * 8 + rr;
        float mc[CCH], lc[CCH];
        float M = -3e38f;
#pragma unroll
        for (int c = 0; c < CCH; ++c) {
            mc[c] = pM[(size_t)c * NN + row];
            lc[c] = pL[(size_t)c * NN + row];
            M = fmaxf(M, mc[c]);
        }
        float L = 0.f, acc = 0.f;
#pragma unroll
        for (int c = 0; c < CCH; ++c) {
            const float wgt = __expf(mc[c] - M);
            L += wgt * lc[c];
            acc += wgt * (float)pO[((size_t)c * NN + row) * DD + n];
        }
        out[(size_t)row * DD + n] = acc / L;
    }
}

extern "C" void kernel_launch(void* const* d_in, const int* in_sizes, int n_in,
                              void* d_out, int out_size, void* d_ws, size_t ws_size,
                              hipStream_t stream) {
    const float* X = (const float*)d_in[0];
    const int* A = (const int*)d_in[1];
    const float* Wq = (const float*)d_in[2];
    const float* Wk = (const float*)d_in[3];
    const float* Wv = (const float*)d_in[4];
    float* out = (float*)d_out;

    char* ws = (char*)d_ws;
    const size_t MB = 1ull << 20;
    f16* Xh = (f16*)(ws + 0 * MB);
    f16* Xl = (f16*)(ws + 4 * MB);
    f16* WtH = (f16*)(ws + 8 * MB);
    f16* WtL = (f16*)(ws + 8 * MB + 512 * 1024);
    f16* Qh = (f16*)(ws + 9 * MB);
    f16* Ql = (f16*)(ws + 13 * MB);
    f16* Kh = (f16*)(ws + 17 * MB);
    f16* Vt = (f16*)(ws + 21 * MB);
    f16* pO = (f16*)(ws + 25 * MB);  // 8 chunks x 8192 x 256 f16 = 32 MB
    float* pM = (float*)(ws + 57 * MB);
    float* pL = (float*)(ws + 57 * MB + 256 * 1024);
    (void)ws_size; (void)in_sizes; (void)n_in; (void)out_size;

    splitX_kernel<<<2048, 256, 0, stream>>>((const float4*)X, (f16x4*)Xh, (f16x4*)Xl);
    splitW_kernel<<<768, 256, 0, stream>>>(Wq, Wk, Wv, WtH, WtL);
    qkv_kernel<<<dim3(NN / 64, 3), 256, 0, stream>>>(Xh, Xl, WtH, WtL, Qh, Ql, Kh, Vt);
    flash_kernel<<<(NN / BR) * CCH, 512, 0, stream>>>(Qh, Ql, Kh, Vt, A, pO, pM, pL);
    merge_kernel<<<NN / 8, 256, 0, stream>>>(pO, pM, pL, out);
}

// Round 12
// 523.931 us; speedup vs baseline: 1.4674x; 1.4674x over previous
//
#include <hip/hip_runtime.h>
#include <stdint.h>

// GATConv fused v12 = v11 with __launch_bounds__(512, 2).
// R11 post-mortem: HIP's 2nd launch_bounds arg acts as min BLOCKS/CU (CUDA
// semantics): (512,4) -> 32 waves/CU -> 64-VGPR budget -> total spill
// (FETCH 1.35 GB, MfmaUtil 9%). (512,2) -> 128-VGPR budget (kernel needs
// ~124, proven v5). 80 KB LDS still admits 2 blocks/CU (46% occ seen in R11).

typedef _Float16 f16;
typedef unsigned short u16;
typedef __attribute__((ext_vector_type(8))) _Float16 f16x8;
typedef __attribute__((ext_vector_type(4))) _Float16 f16x4;
typedef __attribute__((ext_vector_type(4))) float f32x4;

#define NN 8192
#define DD 256
#define BR 128
#define BC 64
#define CCH 8
#define COLS (NN / CCH)  // 1024
#define NIT (COLS / BC)  // 16

#define MFMA(a, b, c) __builtin_amdgcn_mfma_f32_16x16x32_f16((a), (b), (c), 0, 0, 0)

__device__ __forceinline__ void gl2lds16(const void* g, void* l) {
    __builtin_amdgcn_global_load_lds(
        (const __attribute__((address_space(1))) unsigned int*)g,
        (__attribute__((address_space(3))) unsigned int*)l, 16, 0, 0);
}

__device__ __forceinline__ u16 f16bits(f16 h) {
    union { f16 h; u16 u; } c;
    c.h = h;
    return c.u;
}

// P row swizzle: distinct 16B-block offsets across quads
__device__ __forceinline__ int pswz(int row) { return (row ^ (row >> 2)) & 7; }

// ---------------- split X to fp16 hi/lo (4 elems/thread) ----------------
__global__ void splitX_kernel(const float4* __restrict__ X, f16x4* __restrict__ Xh,
                              f16x4* __restrict__ Xl) {
    const int i = blockIdx.x * blockDim.x + threadIdx.x;  // 524288
    const float4 v = X[i];
    const f16 h0 = (f16)v.x, h1 = (f16)v.y, h2 = (f16)v.z, h3 = (f16)v.w;
    f16x4 H = {h0, h1, h2, h3};
    f16x4 L = {(f16)(v.x - (float)h0), (f16)(v.y - (float)h1), (f16)(v.z - (float)h2),
               (f16)(v.w - (float)h3)};
    Xh[i] = H;
    Xl[i] = L;
}

// W[k][n] (3 mats 256x256) -> Wt[(mat*256+n)][k] fp16 hi/lo (transposed)
__global__ void splitW_kernel(const float* __restrict__ Wq, const float* __restrict__ Wk,
                              const float* __restrict__ Wv, f16* __restrict__ WtH,
                              f16* __restrict__ WtL) {
    const int i = blockIdx.x * blockDim.x + threadIdx.x;  // 3*65536
    const int mat = i >> 16;
    const int k = (i >> 8) & 255;
    const int n = i & 255;
    const float* W = (mat == 0) ? Wq : ((mat == 1) ? Wk : Wv);
    const float v = W[k * 256 + n];
    const f16 h = (f16)v;
    const size_t o = (size_t)(mat * 256 + n) * 256 + k;
    WtH[o] = h;
    WtL[o] = (f16)(v - (float)h);
}

// ---------------- QKV GEMM: LDS-staged W chunks, X frags in registers ----------------
__global__ __launch_bounds__(256, 2) void qkv_kernel(
    const f16* __restrict__ Xh, const f16* __restrict__ Xl,
    const f16* __restrict__ WtH, const f16* __restrict__ WtL,
    f16* __restrict__ Qh, f16* __restrict__ Ql,
    f16* __restrict__ Kh, f16* __restrict__ Vt) {
    __shared__ f16 Wh[64 * 256];
    __shared__ f16 Wl[64 * 256];
    const int lane = threadIdx.x & 63;
    const int w = threadIdx.x >> 6;
    const int l15 = lane & 15;
    const int quad = lane >> 4;
    const int r0 = blockIdx.x * 64;
    const int mat = blockIdx.y;

    f16x8 xh[8], xl[8];
    const size_t xb = (size_t)(r0 + w * 16 + l15) * DD + quad * 8;
#pragma unroll
    for (int kc = 0; kc < 8; ++kc) {
        xh[kc] = *(const f16x8*)(Xh + xb + kc * 32);
        xl[kc] = *(const f16x8*)(Xl + xb + kc * 32);
    }
    const int orow = r0 + w * 16 + quad * 4;

#pragma unroll 1
    for (int c = 0; c < 4; ++c) {
        const int nb = mat * 256 + c * 64;
#pragma unroll
        for (int i = 0; i < 8; ++i) {
            const int r = w * 16 + i * 2 + (lane >> 5);
            gl2lds16(WtH + (size_t)(nb + r) * DD + (((lane & 31) ^ (r & 7)) * 8),
                     &Wh[(w * 16 + i * 2) * 256]);
        }
#pragma unroll
        for (int i = 0; i < 8; ++i) {
            const int r = w * 16 + i * 2 + (lane >> 5);
            gl2lds16(WtL + (size_t)(nb + r) * DD + (((lane & 31) ^ (r & 7)) * 8),
                     &Wl[(w * 16 + i * 2) * 256]);
        }
        __syncthreads();

        const f32x4 fzero = {0.f, 0.f, 0.f, 0.f};
        f32x4 acc[4];
#pragma unroll
        for (int nt = 0; nt < 4; ++nt) acc[nt] = fzero;
#pragma unroll
        for (int kc = 0; kc < 8; ++kc)
#pragma unroll
            for (int nt = 0; nt < 4; ++nt) {
                const int r = nt * 16 + l15;
                const int blk = (((kc * 4 + quad) ^ (r & 7)) * 8);
                const f16x8 wh = *(const f16x8*)&Wh[r * 256 + blk];
                const f16x8 wl = *(const f16x8*)&Wl[r * 256 + blk];
                acc[nt] = MFMA(xh[kc], wh, acc[nt]);
                acc[nt] = MFMA(xh[kc], wl, acc[nt]);
                acc[nt] = MFMA(xl[kc], wh, acc[nt]);
            }

        if (mat == 0) {
#pragma unroll
            for (int nt = 0; nt < 4; ++nt)
#pragma unroll
                for (int rg = 0; rg < 4; ++rg) {
                    const int col = c * 64 + nt * 16 + l15;
                    const float v = acc[nt][rg];
                    const f16 h = (f16)v;
                    Qh[(size_t)(orow + rg) * DD + col] = h;
                    Ql[(size_t)(orow + rg) * DD + col] = (f16)(v - (float)h);
                }
        } else if (mat == 1) {
#pragma unroll
            for (int nt = 0; nt < 4; ++nt)
#pragma unroll
                for (int rg = 0; rg < 4; ++rg) {
                    const int col = c * 64 + nt * 16 + l15;
                    Kh[(size_t)(orow + rg) * DD + col] = (f16)acc[nt][rg];
                }
        } else {
#pragma unroll
            for (int nt = 0; nt < 4; ++nt) {
                const int n = c * 64 + nt * 16 + l15;
                ushort4 pk;
                pk.x = f16bits((f16)acc[nt][0]);
                pk.y = f16bits((f16)acc[nt][1]);
                pk.z = f16bits((f16)acc[nt][2]);
                pk.w = f16bits((f16)acc[nt][3]);
                *(ushort4*)(Vt + (size_t)n * NN + orow) = pk;
            }
        }
        __syncthreads();
    }
}

// ---------------- flash kernel v12 ----------------
// grid 512 linear: cch = bid&7 (pins chunk to XCD), rowblk = bid>>3, BR=128.
// 8 waves x 16 rows, wave-local softmax, single-buffered K/V, 2 barriers/iter;
// LDS exactly 80 KB -> 2 co-resident blocks hide each other's stalls.
__global__ __launch_bounds__(512, 2) void flash_kernel(
    const f16* __restrict__ Qh, const f16* __restrict__ Ql,
    const f16* __restrict__ Kh, const f16* __restrict__ Vt,
    const int* __restrict__ A,
    f16* __restrict__ pO, float* __restrict__ pM, float* __restrict__ pL) {
    __shared__ f16 Klds[64 * 256];    // 32 KB, [j][k] XOR-swizzled by j&7
    __shared__ f16 Vlds[256 * 64];    // 32 KB, [n][j] swizzled by n&7
    __shared__ f16 Plds[8][16 * 64];  // 16 KB, per-wave, pswz 16B-block swizzle

    const int lane = threadIdx.x & 63;
    const int w = threadIdx.x >> 6;  // 0..7
    const int l15 = lane & 15;
    const int quad = lane >> 4;
    const int bid = blockIdx.x;
    const int cch = bid & 7;
    const int r0 = (bid >> 3) * BR;
    const int col0 = cch * COLS;

    // Q fragments resident (A-layout m=l15, k=quad*8+i), hi+lo
    f16x8 qh[8], ql[8];
    {
        const size_t qb = (size_t)(r0 + w * 16 + l15) * DD + quad * 8;
#pragma unroll
        for (int kc = 0; kc < 8; ++kc) {
            qh[kc] = *(const f16x8*)(Qh + qb + kc * 32);
            ql[kc] = *(const f16x8*)(Ql + qb + kc * 32);
        }
    }

    const f32x4 fzero = {0.f, 0.f, 0.f, 0.f};
    f32x4 accO[16];
#pragma unroll
    for (int i = 0; i < 16; ++i) accO[i] = fzero;
    float mrow[4], lpart[4];  // per-lane l partials, reduced in epilogue
#pragma unroll
    for (int r = 0; r < 4; ++r) {
        mrow[r] = -1e30f;
        lpart[r] = 0.f;
    }
    const int growb = r0 + w * 16 + quad * 4;
    f16* Pw = &Plds[w][0];

#pragma unroll 1
    for (int it = 0; it < NIT; ++it) {
        const int j0 = col0 + it * BC;

        // stage K rows w*8..+8 and V n-rows w*32..+32 (single buffer)
#pragma unroll
        for (int i = 0; i < 4; ++i) {
            const int r = w * 8 + i * 2 + (lane >> 5);
            gl2lds16(Kh + (size_t)(j0 + r) * DD + (((lane & 31) ^ (r & 7)) * 8),
                     &Klds[(w * 8 + i * 2) * 256]);
        }
#pragma unroll
        for (int i = 0; i < 4; ++i) {
            const int n = w * 32 + i * 8 + (lane >> 3);
            gl2lds16(Vt + (size_t)n * NN + j0 + (((lane & 7) ^ (n & 7)) * 8),
                     &Vlds[(w * 32 + i * 8) * 64]);
        }

        // adjacency (issued pre-barrier; latency overlaps the staging drain)
        int av[4][4];
#pragma unroll
        for (int rgi = 0; rgi < 4; ++rgi)
#pragma unroll
            for (int jt = 0; jt < 4; ++jt)
                av[rgi][jt] = __builtin_nontemporal_load(
                    A + (size_t)(growb + rgi) * NN + j0 + jt * 16 + l15);

        __syncthreads();  // B1: staging visible (co-resident block computes now)

        // S = (Qh+Ql)·Kh^T : 16 rows x 64 cols per wave
        f32x4 accS[4];
#pragma unroll
        for (int jt = 0; jt < 4; ++jt) accS[jt] = fzero;
#pragma unroll
        for (int kc = 0; kc < 8; ++kc)
#pragma unroll
            for (int jt = 0; jt < 4; ++jt) {
                const int r = jt * 16 + l15;
                const f16x8 kf =
                    *(const f16x8*)&Klds[r * 256 + (((kc * 4 + quad) ^ (r & 7)) * 8)];
                accS[jt] = MFMA(qh[kc], kf, accS[jt]);
                accS[jt] = MFMA(ql[kc], kf, accS[jt]);
            }

        // wave-local online softmax (f32 shfl max; l-sum deferred)
        float alpha[4];
#pragma unroll
        for (int rgi = 0; rgi < 4; ++rgi) {
            const int gr = growb + rgi;
            float mx = -3.0e38f;
#pragma unroll
            for (int jt = 0; jt < 4; ++jt) {
                const int gc = j0 + jt * 16 + l15;
                const float s = (av[rgi][jt] != 0 || gr == gc) ? accS[jt][rgi] : -3.0e38f;
                accS[jt][rgi] = s;
                mx = fmaxf(mx, s);
            }
#pragma unroll
            for (int off = 1; off < 16; off <<= 1) mx = fmaxf(mx, __shfl_xor(mx, off, 64));
            const float mnew = fmaxf(mrow[rgi], mx);
            alpha[rgi] = __expf(mrow[rgi] - mnew);
            mrow[rgi] = mnew;
            float rs = 0.f;
            const int lrow = quad * 4 + rgi;
#pragma unroll
            for (int jt = 0; jt < 4; ++jt) {
                const float s = accS[jt][rgi];
                const float e = (s > -1.0e37f) ? __expf(s - mnew) : 0.f;
                rs += e;
                const int col = jt * 16 + l15;
                Pw[lrow * 64 + (((col >> 3) ^ pswz(lrow)) * 8) + (col & 7)] = (f16)e;
            }
            lpart[rgi] = lpart[rgi] * alpha[rgi] + rs;
        }
#pragma unroll
        for (int nt = 0; nt < 16; ++nt)
#pragma unroll
            for (int rgi = 0; rgi < 4; ++rgi) accO[nt][rgi] *= alpha[rgi];

        // P A-frags (per-wave LDS round trip; in-order, no barrier)
        f16x8 pf[2];
        pf[0] = *(const f16x8*)&Pw[l15 * 64 + (((0 * 4 + quad) ^ pswz(l15)) * 8)];
        pf[1] = *(const f16x8*)&Pw[l15 * 64 + (((1 * 4 + quad) ^ pswz(l15)) * 8)];

        // PV: 16 rows x 256 n per wave
#pragma unroll
        for (int nt = 0; nt < 16; ++nt)
#pragma unroll
            for (int kc2 = 0; kc2 < 2; ++kc2) {
                const int n = nt * 16 + l15;
                const f16x8 vf =
                    *(const f16x8*)&Vlds[n * 64 + (((kc2 * 4 + quad) ^ (n & 7)) * 8)];
                accO[nt] = MFMA(pf[kc2], vf, accO[nt]);
            }

        __syncthreads();  // B2: compute done; LDS reusable next iter
    }

    // epilogue: reduce per-lane l partials across 16 lanes (once)
#pragma unroll
    for (int rgi = 0; rgi < 4; ++rgi)
#pragma unroll
        for (int off = 1; off < 16; off <<= 1)
            lpart[rgi] += __shfl_xor(lpart[rgi], off, 64);

    // write partials (f16 unnormalized O: |O| <= l*maxV << f16 max)
#pragma unroll
    for (int nt = 0; nt < 16; ++nt)
#pragma unroll
        for (int rgi = 0; rgi < 4; ++rgi)
            pO[((size_t)cch * NN + growb + rgi) * DD + nt * 16 + l15] =
                (f16)accO[nt][rgi];
    if (l15 == 0) {
#pragma unroll
        for (int rgi = 0; rgi < 4; ++rgi) {
            pM[(size_t)cch * NN + growb + rgi] = mrow[rgi];
            pL[(size_t)cch * NN + growb + rgi] = lpart[rgi];
        }
    }
}

// ---------------- merge partials (8 rows/block) ----------------
__global__ __launch_bounds__(256) void merge_kernel(const f16* __restrict__ pO,
                                                    const float* __restrict__ pM,
                                                    const float* __restrict__ pL,
                                                    float* __restrict__ out) {
    const int n = threadIdx.x;
#pragma unroll 1
    for (int rr = 0; rr < 8; ++rr) {
        const int row = blockIdx.x * 8 + rr;
        float mc[CCH], lc[CCH];
        float M = -3e38f;
#pragma unroll
        for (int c = 0; c < CCH; ++c) {
            mc[c] = pM[(size_t)c * NN + row];
            lc[c] = pL[(size_t)c * NN + row];
            M = fmaxf(M, mc[c]);
        }
        float L = 0.f, acc = 0.f;
#pragma unroll
        for (int c = 0; c < CCH; ++c) {
            const float wgt = __expf(mc[c] - M);
            L += wgt * lc[c];
            acc += wgt * (float)pO[((size_t)c * NN + row) * DD + n];
        }
        out[(size_t)row * DD + n] = acc / L;
    }
}

extern "C" void kernel_launch(void* const* d_in, const int* in_sizes, int n_in,
                              void* d_out, int out_size, void* d_ws, size_t ws_size,
                              hipStream_t stream) {
    const float* X = (const float*)d_in[0];
    const int* A = (const int*)d_in[1];
    const float* Wq = (const float*)d_in[2];
    const float* Wk = (const float*)d_in[3];
    const float* Wv = (const float*)d_in[4];
    float* out = (float*)d_out;

    char* ws = (char*)d_ws;
    const size_t MB = 1ull << 20;
    f16* Xh = (f16*)(ws + 0 * MB);
    f16* Xl = (f16*)(ws + 4 * MB);
    f16* WtH = (f16*)(ws + 8 * MB);
    f16* WtL = (f16*)(ws + 8 * MB + 512 * 1024);
    f16* Qh = (f16*)(ws + 9 * MB);
    f16* Ql = (f16*)(ws + 13 * MB);
    f16* Kh = (f16*)(ws + 17 * MB);
    f16* Vt = (f16*)(ws + 21 * MB);
    f16* pO = (f16*)(ws + 25 * MB);  // 8 chunks x 8192 x 256 f16 = 32 MB
    float* pM = (float*)(ws + 57 * MB);
    float* pL = (float*)(ws + 57 * MB + 256 * 1024);
    (void)ws_size; (void)in_sizes; (void)n_in; (void)out_size;

    splitX_kernel<<<2048, 256, 0, stream>>>((const float4*)X, (f16x4*)Xh, (f16x4*)Xl);
    splitW_kernel<<<768, 256, 0, stream>>>(Wq, Wk, Wv, WtH, WtL);
    qkv_kernel<<<dim3(NN / 64, 3), 256, 0, stream>>>(Xh, Xl, WtH, WtL, Qh, Ql, Kh, Vt);
    flash_kernel<<<(NN / BR) * CCH, 512, 0, stream>>>(Qh, Ql, Kh, Vt, A, pO, pM, pL);
    merge_kernel<<<NN / 8, 256, 0, stream>>>(pO, pM, pL, out);
}

// Round 13
// 498.812 us; speedup vs baseline: 1.5413x; 1.0504x over previous
//
#include <hip/hip_runtime.h>
#include <stdint.h>

// GATConv fused v13: fit 128 unified regs/wave -> 2 blocks/CU for real.
// R12 forensics: unified VGPR+AGPR file means VGPR_Count=128 + ~80 AGPR acc
// -> 192/wave -> 1 block. Cuts: (1) drop Ql from S (single Qh*Kh MFMA; logit
// noise 0.012*sqrt2, absmax est ~0.12 < 0.18), (2) pack adjacency to a 16-bit
// mask at load (kills av[16] live range). qh32+accO64+accS16+misc ~ 124.
// Structure: CCH=8, BR=128, single-buffered 80KB LDS, launch_bounds(512,2).

typedef _Float16 f16;
typedef unsigned short u16;
typedef __attribute__((ext_vector_type(8))) _Float16 f16x8;
typedef __attribute__((ext_vector_type(4))) _Float16 f16x4;
typedef __attribute__((ext_vector_type(4))) float f32x4;

#define NN 8192
#define DD 256
#define BR 128
#define BC 64
#define CCH 8
#define COLS (NN / CCH)  // 1024
#define NIT (COLS / BC)  // 16

#define MFMA(a, b, c) __builtin_amdgcn_mfma_f32_16x16x32_f16((a), (b), (c), 0, 0, 0)

__device__ __forceinline__ void gl2lds16(const void* g, void* l) {
    __builtin_amdgcn_global_load_lds(
        (const __attribute__((address_space(1))) unsigned int*)g,
        (__attribute__((address_space(3))) unsigned int*)l, 16, 0, 0);
}

__device__ __forceinline__ u16 f16bits(f16 h) {
    union { f16 h; u16 u; } c;
    c.h = h;
    return c.u;
}

// P row swizzle: distinct 16B-block offsets across quads
__device__ __forceinline__ int pswz(int row) { return (row ^ (row >> 2)) & 7; }

// ---------------- split X to fp16 hi/lo (4 elems/thread) ----------------
__global__ void splitX_kernel(const float4* __restrict__ X, f16x4* __restrict__ Xh,
                              f16x4* __restrict__ Xl) {
    const int i = blockIdx.x * blockDim.x + threadIdx.x;  // 524288
    const float4 v = X[i];
    const f16 h0 = (f16)v.x, h1 = (f16)v.y, h2 = (f16)v.z, h3 = (f16)v.w;
    f16x4 H = {h0, h1, h2, h3};
    f16x4 L = {(f16)(v.x - (float)h0), (f16)(v.y - (float)h1), (f16)(v.z - (float)h2),
               (f16)(v.w - (float)h3)};
    Xh[i] = H;
    Xl[i] = L;
}

// W[k][n] (3 mats 256x256) -> Wt[(mat*256+n)][k] fp16 hi/lo (transposed)
__global__ void splitW_kernel(const float* __restrict__ Wq, const float* __restrict__ Wk,
                              const float* __restrict__ Wv, f16* __restrict__ WtH,
                              f16* __restrict__ WtL) {
    const int i = blockIdx.x * blockDim.x + threadIdx.x;  // 3*65536
    const int mat = i >> 16;
    const int k = (i >> 8) & 255;
    const int n = i & 255;
    const float* W = (mat == 0) ? Wq : ((mat == 1) ? Wk : Wv);
    const float v = W[k * 256 + n];
    const f16 h = (f16)v;
    const size_t o = (size_t)(mat * 256 + n) * 256 + k;
    WtH[o] = h;
    WtL[o] = (f16)(v - (float)h);
}

// ---------------- QKV GEMM: LDS-staged W chunks, X frags in registers ----------------
__global__ __launch_bounds__(256, 2) void qkv_kernel(
    const f16* __restrict__ Xh, const f16* __restrict__ Xl,
    const f16* __restrict__ WtH, const f16* __restrict__ WtL,
    f16* __restrict__ Qh, f16* __restrict__ Kh, f16* __restrict__ Vt) {
    __shared__ f16 Wh[64 * 256];
    __shared__ f16 Wl[64 * 256];
    const int lane = threadIdx.x & 63;
    const int w = threadIdx.x >> 6;
    const int l15 = lane & 15;
    const int quad = lane >> 4;
    const int r0 = blockIdx.x * 64;
    const int mat = blockIdx.y;

    f16x8 xh[8], xl[8];
    const size_t xb = (size_t)(r0 + w * 16 + l15) * DD + quad * 8;
#pragma unroll
    for (int kc = 0; kc < 8; ++kc) {
        xh[kc] = *(const f16x8*)(Xh + xb + kc * 32);
        xl[kc] = *(const f16x8*)(Xl + xb + kc * 32);
    }
    const int orow = r0 + w * 16 + quad * 4;

#pragma unroll 1
    for (int c = 0; c < 4; ++c) {
        const int nb = mat * 256 + c * 64;
#pragma unroll
        for (int i = 0; i < 8; ++i) {
            const int r = w * 16 + i * 2 + (lane >> 5);
            gl2lds16(WtH + (size_t)(nb + r) * DD + (((lane & 31) ^ (r & 7)) * 8),
                     &Wh[(w * 16 + i * 2) * 256]);
        }
#pragma unroll
        for (int i = 0; i < 8; ++i) {
            const int r = w * 16 + i * 2 + (lane >> 5);
            gl2lds16(WtL + (size_t)(nb + r) * DD + (((lane & 31) ^ (r & 7)) * 8),
                     &Wl[(w * 16 + i * 2) * 256]);
        }
        __syncthreads();

        const f32x4 fzero = {0.f, 0.f, 0.f, 0.f};
        f32x4 acc[4];
#pragma unroll
        for (int nt = 0; nt < 4; ++nt) acc[nt] = fzero;
#pragma unroll
        for (int kc = 0; kc < 8; ++kc)
#pragma unroll
            for (int nt = 0; nt < 4; ++nt) {
                const int r = nt * 16 + l15;
                const int blk = (((kc * 4 + quad) ^ (r & 7)) * 8);
                const f16x8 wh = *(const f16x8*)&Wh[r * 256 + blk];
                const f16x8 wl = *(const f16x8*)&Wl[r * 256 + blk];
                acc[nt] = MFMA(xh[kc], wh, acc[nt]);
                acc[nt] = MFMA(xh[kc], wl, acc[nt]);
                acc[nt] = MFMA(xl[kc], wh, acc[nt]);
            }

        if (mat == 0) {
#pragma unroll
            for (int nt = 0; nt < 4; ++nt)
#pragma unroll
                for (int rg = 0; rg < 4; ++rg) {
                    const int col = c * 64 + nt * 16 + l15;
                    Qh[(size_t)(orow + rg) * DD + col] = (f16)acc[nt][rg];
                }
        } else if (mat == 1) {
#pragma unroll
            for (int nt = 0; nt < 4; ++nt)
#pragma unroll
                for (int rg = 0; rg < 4; ++rg) {
                    const int col = c * 64 + nt * 16 + l15;
                    Kh[(size_t)(orow + rg) * DD + col] = (f16)acc[nt][rg];
                }
        } else {
#pragma unroll
            for (int nt = 0; nt < 4; ++nt) {
                const int n = c * 64 + nt * 16 + l15;
                ushort4 pk;
                pk.x = f16bits((f16)acc[nt][0]);
                pk.y = f16bits((f16)acc[nt][1]);
                pk.z = f16bits((f16)acc[nt][2]);
                pk.w = f16bits((f16)acc[nt][3]);
                *(ushort4*)(Vt + (size_t)n * NN + orow) = pk;
            }
        }
        __syncthreads();
    }
}

// ---------------- flash kernel v13 ----------------
// grid 512 linear: cch = bid&7, rowblk = bid>>3, BR=128, 8 waves x 16 rows.
// Single-buffered K/V, 2 barriers/iter; target 2 blocks/CU (<=128 regs/wave).
__global__ __launch_bounds__(512, 2) void flash_kernel(
    const f16* __restrict__ Qh, const f16* __restrict__ Kh,
    const f16* __restrict__ Vt, const int* __restrict__ A,
    f16* __restrict__ pO, float* __restrict__ pM, float* __restrict__ pL) {
    __shared__ f16 Klds[64 * 256];    // 32 KB, [j][k] XOR-swizzled by j&7
    __shared__ f16 Vlds[256 * 64];    // 32 KB, [n][j] swizzled by n&7
    __shared__ f16 Plds[8][16 * 64];  // 16 KB, per-wave, pswz swizzle
                                      // total exactly 80 KB

    const int lane = threadIdx.x & 63;
    const int w = threadIdx.x >> 6;  // 0..7
    const int l15 = lane & 15;
    const int quad = lane >> 4;
    const int bid = blockIdx.x;
    const int cch = bid & 7;
    const int r0 = (bid >> 3) * BR;
    const int col0 = cch * COLS;

    // Q fragments resident (A-layout m=l15, k=quad*8+i), hi ONLY (32 VGPRs)
    f16x8 qh[8];
    {
        const size_t qb = (size_t)(r0 + w * 16 + l15) * DD + quad * 8;
#pragma unroll
        for (int kc = 0; kc < 8; ++kc) qh[kc] = *(const f16x8*)(Qh + qb + kc * 32);
    }

    const f32x4 fzero = {0.f, 0.f, 0.f, 0.f};
    f32x4 accO[16];
#pragma unroll
    for (int i = 0; i < 16; ++i) accO[i] = fzero;
    float mrow[4], lpart[4];  // per-lane l partials, reduced in epilogue
#pragma unroll
    for (int r = 0; r < 4; ++r) {
        mrow[r] = -1e30f;
        lpart[r] = 0.f;
    }
    const int growb = r0 + w * 16 + quad * 4;
    f16* Pw = &Plds[w][0];

#pragma unroll 1
    for (int it = 0; it < NIT; ++it) {
        const int j0 = col0 + it * BC;

        // stage K rows w*8..+8 and V n-rows w*32..+32 (single buffer)
#pragma unroll
        for (int i = 0; i < 4; ++i) {
            const int r = w * 8 + i * 2 + (lane >> 5);
            gl2lds16(Kh + (size_t)(j0 + r) * DD + (((lane & 31) ^ (r & 7)) * 8),
                     &Klds[(w * 8 + i * 2) * 256]);
        }
#pragma unroll
        for (int i = 0; i < 4; ++i) {
            const int n = w * 32 + i * 8 + (lane >> 3);
            gl2lds16(Vt + (size_t)n * NN + j0 + (((lane & 7) ^ (n & 7)) * 8),
                     &Vlds[(w * 32 + i * 8) * 64]);
        }

        // adjacency -> 16-bit lane mask (diagonal folded in); short live range
        unsigned msk = 0;
#pragma unroll
        for (int rgi = 0; rgi < 4; ++rgi)
#pragma unroll
            for (int jt = 0; jt < 4; ++jt) {
                const int gc = j0 + jt * 16 + l15;
                const int a = __builtin_nontemporal_load(
                    A + (size_t)(growb + rgi) * NN + gc);
                msk |= ((a != 0 || (growb + rgi) == gc) ? 1u : 0u) << (rgi * 4 + jt);
            }

        __syncthreads();  // B1: staging visible

        // S = Qh·Kh^T : 16 rows x 64 cols per wave (single-term fp16)
        f32x4 accS[4];
#pragma unroll
        for (int jt = 0; jt < 4; ++jt) accS[jt] = fzero;
#pragma unroll
        for (int kc = 0; kc < 8; ++kc)
#pragma unroll
            for (int jt = 0; jt < 4; ++jt) {
                const int r = jt * 16 + l15;
                const f16x8 kf =
                    *(const f16x8*)&Klds[r * 256 + (((kc * 4 + quad) ^ (r & 7)) * 8)];
                accS[jt] = MFMA(qh[kc], kf, accS[jt]);
            }

        // wave-local online softmax (f32 shfl max; l-sum deferred)
        float alpha[4];
#pragma unroll
        for (int rgi = 0; rgi < 4; ++rgi) {
            float mx = -3.0e38f;
#pragma unroll
            for (int jt = 0; jt < 4; ++jt) {
                const float s =
                    ((msk >> (rgi * 4 + jt)) & 1) ? accS[jt][rgi] : -3.0e38f;
                accS[jt][rgi] = s;
                mx = fmaxf(mx, s);
            }
#pragma unroll
            for (int off = 1; off < 16; off <<= 1) mx = fmaxf(mx, __shfl_xor(mx, off, 64));
            const float mnew = fmaxf(mrow[rgi], mx);
            alpha[rgi] = __expf(mrow[rgi] - mnew);
            mrow[rgi] = mnew;
            float rs = 0.f;
            const int lrow = quad * 4 + rgi;
#pragma unroll
            for (int jt = 0; jt < 4; ++jt) {
                const float s = accS[jt][rgi];
                const float e = (s > -1.0e37f) ? __expf(s - mnew) : 0.f;
                rs += e;
                const int col = jt * 16 + l15;
                Pw[lrow * 64 + (((col >> 3) ^ pswz(lrow)) * 8) + (col & 7)] = (f16)e;
            }
            lpart[rgi] = lpart[rgi] * alpha[rgi] + rs;
        }
#pragma unroll
        for (int nt = 0; nt < 16; ++nt)
#pragma unroll
            for (int rgi = 0; rgi < 4; ++rgi) accO[nt][rgi] *= alpha[rgi];

        // P A-frags (per-wave LDS round trip; in-order, no barrier)
        f16x8 pf[2];
        pf[0] = *(const f16x8*)&Pw[l15 * 64 + ((quad ^ pswz(l15)) * 8)];
        pf[1] = *(const f16x8*)&Pw[l15 * 64 + (((4 + quad) ^ pswz(l15)) * 8)];

        // PV: 16 rows x 256 n per wave
#pragma unroll
        for (int nt = 0; nt < 16; ++nt)
#pragma unroll
            for (int kc2 = 0; kc2 < 2; ++kc2) {
                const int n = nt * 16 + l15;
                const f16x8 vf =
                    *(const f16x8*)&Vlds[n * 64 + (((kc2 * 4 + quad) ^ (n & 7)) * 8)];
                accO[nt] = MFMA(pf[kc2], vf, accO[nt]);
            }

        __syncthreads();  // B2: compute done; LDS reusable next iter
    }

    // epilogue: reduce per-lane l partials across 16 lanes (once)
#pragma unroll
    for (int rgi = 0; rgi < 4; ++rgi)
#pragma unroll
        for (int off = 1; off < 16; off <<= 1)
            lpart[rgi] += __shfl_xor(lpart[rgi], off, 64);

    // write partials (f16 unnormalized O)
#pragma unroll
    for (int nt = 0; nt < 16; ++nt)
#pragma unroll
        for (int rgi = 0; rgi < 4; ++rgi)
            pO[((size_t)cch * NN + growb + rgi) * DD + nt * 16 + l15] =
                (f16)accO[nt][rgi];
    if (l15 == 0) {
#pragma unroll
        for (int rgi = 0; rgi < 4; ++rgi) {
            pM[(size_t)cch * NN + growb + rgi] = mrow[rgi];
            pL[(size_t)cch * NN + growb + rgi] = lpart[rgi];
        }
    }
}

// ---------------- merge partials (8 rows/block) ----------------
__global__ __launch_bounds__(256) void merge_kernel(const f16* __restrict__ pO,
                                                    const float* __restrict__ pM,
                                                    const float* __restrict__ pL,
                                                    float* __restrict__ out) {
    const int n = threadIdx.x;
#pragma unroll 1
    for (int rr = 0; rr < 8; ++rr) {
        const int row = blockIdx.x * 8 + rr;
        float mc[CCH], lc[CCH];
        float M = -3e38f;
#pragma unroll
        for (int c = 0; c < CCH; ++c) {
            mc[c] = pM[(size_t)c * NN + row];
            lc[c] = pL[(size_t)c * NN + row];
            M = fmaxf(M, mc[c]);
        }
        float L = 0.f, acc = 0.f;
#pragma unroll
        for (int c = 0; c < CCH; ++c) {
            const float wgt = __expf(mc[c] - M);
            L += wgt * lc[c];
            acc += wgt * (float)pO[((size_t)c * NN + row) * DD + n];
        }
        out[(size_t)row * DD + n] = acc / L;
    }
}

extern "C" void kernel_launch(void* const* d_in, const int* in_sizes, int n_in,
                              void* d_out, int out_size, void* d_ws, size_t ws_size,
                              hipStream_t stream) {
    const float* X = (const float*)d_in[0];
    const int* A = (const int*)d_in[1];
    const float* Wq = (const float*)d_in[2];
    const float* Wk = (const float*)d_in[3];
    const float* Wv = (const float*)d_in[4];
    float* out = (float*)d_out;

    char* ws = (char*)d_ws;
    const size_t MB = 1ull << 20;
    f16* Xh = (f16*)(ws + 0 * MB);
    f16* Xl = (f16*)(ws + 4 * MB);
    f16* WtH = (f16*)(ws + 8 * MB);
    f16* WtL = (f16*)(ws + 8 * MB + 512 * 1024);
    f16* Qh = (f16*)(ws + 9 * MB);
    f16* Kh = (f16*)(ws + 17 * MB);
    f16* Vt = (f16*)(ws + 21 * MB);
    f16* pO = (f16*)(ws + 25 * MB);  // 8 chunks x 8192 x 256 f16 = 32 MB
    float* pM = (float*)(ws + 57 * MB);
    float* pL = (float*)(ws + 57 * MB + 256 * 1024);
    (void)ws_size; (void)in_sizes; (void)n_in; (void)out_size;

    splitX_kernel<<<2048, 256, 0, stream>>>((const float4*)X, (f16x4*)Xh, (f16x4*)Xl);
    splitW_kernel<<<768, 256, 0, stream>>>(Wq, Wk, Wv, WtH, WtL);
    qkv_kernel<<<dim3(NN / 64, 3), 256, 0, stream>>>(Xh, Xl, WtH, WtL, Qh, Kh, Vt);
    flash_kernel<<<(NN / BR) * CCH, 512, 0, stream>>>(Qh, Kh, Vt, A, pO, pM, pL);
    merge_kernel<<<NN / 8, 256, 0, stream>>>(pO, pM, pL, out);
}